// Round 1
// baseline (110.346 us; speedup 1.0000x reference)
//
#include <hip/hip_runtime.h>

#define NCH   192
#define TOTAL (16 * 192 * 64 * 64)   // 12,582,912
#define NV4   (TOTAL / 4)            // 3,145,728 float4s; 1024 float4 per (b,c) slice

struct Params {
    float m0[3], b0[3], tf0[3];
    float m1[9], b1[3], tf1[3];
    float m2[9], b2[3], tf2[3];
    float m3[9], b3[3], tf3[3];
    float m4[3], b4;
    float pad[6];
};
static_assert(sizeof(Params) == 64 * sizeof(float), "Params must be 64 floats");

__device__ __forceinline__ float softplusf(float x) {
    // numerically stable log(1+exp(x)); one-time cost, use accurate-ish form
    return (x > 0.f) ? x + log1pf(__expf(-x)) : log1pf(__expf(x));
}

__global__ void eb_precompute(const float* __restrict__ m0, const float* __restrict__ b0, const float* __restrict__ f0,
                              const float* __restrict__ m1, const float* __restrict__ b1, const float* __restrict__ f1,
                              const float* __restrict__ m2, const float* __restrict__ b2, const float* __restrict__ f2,
                              const float* __restrict__ m3, const float* __restrict__ b3, const float* __restrict__ f3,
                              const float* __restrict__ m4, const float* __restrict__ b4,
                              Params* __restrict__ P) {
    int c = blockIdx.x * blockDim.x + threadIdx.x;
    if (c >= NCH) return;
    Params p;
#pragma unroll
    for (int j = 0; j < 3; ++j) {
        p.m0[j]  = softplusf(m0[c * 3 + j]);
        p.b0[j]  = b0[c * 3 + j];
        p.tf0[j] = tanhf(f0[c * 3 + j]);
        p.b1[j]  = b1[c * 3 + j];
        p.tf1[j] = tanhf(f1[c * 3 + j]);
        p.b2[j]  = b2[c * 3 + j];
        p.tf2[j] = tanhf(f2[c * 3 + j]);
        p.b3[j]  = b3[c * 3 + j];
        p.tf3[j] = tanhf(f3[c * 3 + j]);
        p.m4[j]  = softplusf(m4[c * 3 + j]);
    }
#pragma unroll
    for (int j = 0; j < 9; ++j) {
        p.m1[j] = softplusf(m1[c * 9 + j]);
        p.m2[j] = softplusf(m2[c * 9 + j]);
        p.m3[j] = softplusf(m3[c * 9 + j]);
    }
    p.b4 = b4[c];
#pragma unroll
    for (int j = 0; j < 6; ++j) p.pad[j] = 0.f;
    P[c] = p;
}

__device__ __forceinline__ float fast_tanh(float x) {
    // tanh(x) = 1 - 2/(exp(2x)+1); exp overflow -> inf -> rcp -> 0 -> 1 (correct limit)
    float e = __expf(2.0f * x);
    return 1.0f - 2.0f * __builtin_amdgcn_rcpf(e + 1.0f);
}

__device__ __forceinline__ float fast_sigmoid(float x) {
    return __builtin_amdgcn_rcpf(1.0f + __expf(-x));
}

__device__ __forceinline__ float evalnet(float u, const Params& p) {
    float v0 = fmaf(p.m0[0], u, p.b0[0]);
    float v1 = fmaf(p.m0[1], u, p.b0[1]);
    float v2 = fmaf(p.m0[2], u, p.b0[2]);
    v0 = fmaf(p.tf0[0], fast_tanh(v0), v0);
    v1 = fmaf(p.tf0[1], fast_tanh(v1), v1);
    v2 = fmaf(p.tf0[2], fast_tanh(v2), v2);

    float w0 = fmaf(p.m1[0], v0, fmaf(p.m1[1], v1, fmaf(p.m1[2], v2, p.b1[0])));
    float w1 = fmaf(p.m1[3], v0, fmaf(p.m1[4], v1, fmaf(p.m1[5], v2, p.b1[1])));
    float w2 = fmaf(p.m1[6], v0, fmaf(p.m1[7], v1, fmaf(p.m1[8], v2, p.b1[2])));
    w0 = fmaf(p.tf1[0], fast_tanh(w0), w0);
    w1 = fmaf(p.tf1[1], fast_tanh(w1), w1);
    w2 = fmaf(p.tf1[2], fast_tanh(w2), w2);

    float y0 = fmaf(p.m2[0], w0, fmaf(p.m2[1], w1, fmaf(p.m2[2], w2, p.b2[0])));
    float y1 = fmaf(p.m2[3], w0, fmaf(p.m2[4], w1, fmaf(p.m2[5], w2, p.b2[1])));
    float y2 = fmaf(p.m2[6], w0, fmaf(p.m2[7], w1, fmaf(p.m2[8], w2, p.b2[2])));
    y0 = fmaf(p.tf2[0], fast_tanh(y0), y0);
    y1 = fmaf(p.tf2[1], fast_tanh(y1), y1);
    y2 = fmaf(p.tf2[2], fast_tanh(y2), y2);

    float z0 = fmaf(p.m3[0], y0, fmaf(p.m3[1], y1, fmaf(p.m3[2], y2, p.b3[0])));
    float z1 = fmaf(p.m3[3], y0, fmaf(p.m3[4], y1, fmaf(p.m3[5], y2, p.b3[1])));
    float z2 = fmaf(p.m3[6], y0, fmaf(p.m3[7], y1, fmaf(p.m3[8], y2, p.b3[2])));
    z0 = fmaf(p.tf3[0], fast_tanh(z0), z0);
    z1 = fmaf(p.tf3[1], fast_tanh(z1), z1);
    z2 = fmaf(p.tf3[2], fast_tanh(z2), z2);

    return fmaf(p.m4[0], z0, fmaf(p.m4[1], z1, fmaf(p.m4[2], z2, p.b4)));
}

__device__ __forceinline__ float likelihood_of(float u, const Params& p) {
    float lo = evalnet(u - 0.5f, p);
    float hi = evalnet(u + 0.5f, p);
    float sum = lo + hi;
    float s = (sum > 0.f) ? -1.f : ((sum < 0.f) ? 1.f : 0.f);
    float l = fabsf(fast_sigmoid(s * hi) - fast_sigmoid(s * lo));
    return fmaxf(l, 1e-9f);
}

__global__ __launch_bounds__(256) void eb_main(const float4* __restrict__ x,
                                               const float4* __restrict__ nz,
                                               const Params* __restrict__ P,
                                               float4* __restrict__ out,
                                               float4* __restrict__ lik) {
    int stride = gridDim.x * blockDim.x;
    for (int i = blockIdx.x * blockDim.x + threadIdx.x; i < NV4; i += stride) {
        // 1024 float4 per (b,c) slice; each wave spans 64 consecutive float4s,
        // aligned, so (i>>10) is wave-uniform -> scalar param loads.
        int c = __builtin_amdgcn_readfirstlane((i >> 10) % NCH);
        const Params& p = P[c];

        float4 xv = x[i];
        float4 nv = nz[i];
        float u0 = xv.x + nv.x;
        float u1 = xv.y + nv.y;
        float u2 = xv.z + nv.z;
        float u3 = xv.w + nv.w;

        float4 ov = make_float4(u0, u1, u2, u3);
        float4 lv = make_float4(likelihood_of(u0, p),
                                likelihood_of(u1, p),
                                likelihood_of(u2, p),
                                likelihood_of(u3, p));
        out[i] = ov;
        lik[i] = lv;
    }
}

extern "C" void kernel_launch(void* const* d_in, const int* in_sizes, int n_in,
                              void* d_out, int out_size, void* d_ws, size_t ws_size,
                              hipStream_t stream) {
    // setup_inputs() dict order: x, noise, then per-layer {matrix, bias, [factor]}
    const float* x  = (const float*)d_in[0];
    const float* nz = (const float*)d_in[1];
    const float* m0 = (const float*)d_in[2];
    const float* b0 = (const float*)d_in[3];
    const float* f0 = (const float*)d_in[4];
    const float* m1 = (const float*)d_in[5];
    const float* b1 = (const float*)d_in[6];
    const float* f1 = (const float*)d_in[7];
    const float* m2 = (const float*)d_in[8];
    const float* b2 = (const float*)d_in[9];
    const float* f2 = (const float*)d_in[10];
    const float* m3 = (const float*)d_in[11];
    const float* b3 = (const float*)d_in[12];
    const float* f3 = (const float*)d_in[13];
    const float* m4 = (const float*)d_in[14];
    const float* b4 = (const float*)d_in[15];

    Params* P = (Params*)d_ws;  // 192 * 256 B = 49,152 B of scratch

    eb_precompute<<<1, 256, 0, stream>>>(m0, b0, f0, m1, b1, f1, m2, b2, f2,
                                         m3, b3, f3, m4, b4, P);

    float* out = (float*)d_out;
    float* lik = out + TOTAL;
    eb_main<<<2048, 256, 0, stream>>>((const float4*)x, (const float4*)nz, P,
                                      (float4*)out, (float4*)lik);
}

// Round 2
// 60.099 us; speedup vs baseline: 1.8361x; 1.8361x over previous
//
#include <hip/hip_runtime.h>

#define NCH     192
#define TOTAL   (16 * 192 * 64 * 64)   // 12,582,912
#define NV4     (TOTAL / 4)
#define SLICE   4096                    // H*W elements per (b,c) slice
#define NSLICE  (TOTAL / SLICE)         // 3072
#define NK      1025                    // LUT points, u in [-8,8], h = 1/64
#define LSTRIDE 1028                    // padded stride (floats), 16B-aligned
#define LUT_BYTES ((size_t)NCH * LSTRIDE * 4)

// ---------------- accurate helpers (precompute only) ----------------
__device__ __forceinline__ float softplusf(float x) {
    return (x > 0.f) ? x + log1pf(__expf(-x)) : log1pf(__expf(x));
}
__device__ __forceinline__ float sigmoid_acc(float x) {
    return 1.0f / (1.0f + __expf(-x));
}

struct Net {
    float m0[3], b0[3], tf0[3];
    float m1[9], b1[3], tf1[3];
    float m2[9], b2[3], tf2[3];
    float m3[9], b3[3], tf3[3];
    float m4[3], b4;
};

__device__ __forceinline__ float evalnet_acc(float u, const Net& p) {
    float v0 = fmaf(p.m0[0], u, p.b0[0]);
    float v1 = fmaf(p.m0[1], u, p.b0[1]);
    float v2 = fmaf(p.m0[2], u, p.b0[2]);
    v0 = fmaf(p.tf0[0], tanhf(v0), v0);
    v1 = fmaf(p.tf0[1], tanhf(v1), v1);
    v2 = fmaf(p.tf0[2], tanhf(v2), v2);

    float w0 = fmaf(p.m1[0], v0, fmaf(p.m1[1], v1, fmaf(p.m1[2], v2, p.b1[0])));
    float w1 = fmaf(p.m1[3], v0, fmaf(p.m1[4], v1, fmaf(p.m1[5], v2, p.b1[1])));
    float w2 = fmaf(p.m1[6], v0, fmaf(p.m1[7], v1, fmaf(p.m1[8], v2, p.b1[2])));
    w0 = fmaf(p.tf1[0], tanhf(w0), w0);
    w1 = fmaf(p.tf1[1], tanhf(w1), w1);
    w2 = fmaf(p.tf1[2], tanhf(w2), w2);

    float y0 = fmaf(p.m2[0], w0, fmaf(p.m2[1], w1, fmaf(p.m2[2], w2, p.b2[0])));
    float y1 = fmaf(p.m2[3], w0, fmaf(p.m2[4], w1, fmaf(p.m2[5], w2, p.b2[1])));
    float y2 = fmaf(p.m2[6], w0, fmaf(p.m2[7], w1, fmaf(p.m2[8], w2, p.b2[2])));
    y0 = fmaf(p.tf2[0], tanhf(y0), y0);
    y1 = fmaf(p.tf2[1], tanhf(y1), y1);
    y2 = fmaf(p.tf2[2], tanhf(y2), y2);

    float z0 = fmaf(p.m3[0], y0, fmaf(p.m3[1], y1, fmaf(p.m3[2], y2, p.b3[0])));
    float z1 = fmaf(p.m3[3], y0, fmaf(p.m3[4], y1, fmaf(p.m3[5], y2, p.b3[1])));
    float z2 = fmaf(p.m3[6], y0, fmaf(p.m3[7], y1, fmaf(p.m3[8], y2, p.b3[2])));
    z0 = fmaf(p.tf3[0], tanhf(z0), z0);
    z1 = fmaf(p.tf3[1], tanhf(z1), z1);
    z2 = fmaf(p.tf3[2], tanhf(z2), z2);

    return fmaf(p.m4[0], z0, fmaf(p.m4[1], z1, fmaf(p.m4[2], z2, p.b4)));
}

// Build per-channel likelihood LUT: lut[c][k] = L(-8 + k/64), k in [0,1024].
__global__ __launch_bounds__(256) void eb_build_lut(
        const float* __restrict__ m0, const float* __restrict__ b0, const float* __restrict__ f0,
        const float* __restrict__ m1, const float* __restrict__ b1, const float* __restrict__ f1,
        const float* __restrict__ m2, const float* __restrict__ b2, const float* __restrict__ f2,
        const float* __restrict__ m3, const float* __restrict__ b3, const float* __restrict__ f3,
        const float* __restrict__ m4, const float* __restrict__ b4,
        float* __restrict__ lut) {
    int c = blockIdx.x;   // one block per channel
    Net p;
#pragma unroll
    for (int j = 0; j < 3; ++j) {
        p.m0[j]  = softplusf(m0[c * 3 + j]);
        p.b0[j]  = b0[c * 3 + j];
        p.tf0[j] = tanhf(f0[c * 3 + j]);
        p.b1[j]  = b1[c * 3 + j];
        p.tf1[j] = tanhf(f1[c * 3 + j]);
        p.b2[j]  = b2[c * 3 + j];
        p.tf2[j] = tanhf(f2[c * 3 + j]);
        p.b3[j]  = b3[c * 3 + j];
        p.tf3[j] = tanhf(f3[c * 3 + j]);
        p.m4[j]  = softplusf(m4[c * 3 + j]);
    }
#pragma unroll
    for (int j = 0; j < 9; ++j) {
        p.m1[j] = softplusf(m1[c * 9 + j]);
        p.m2[j] = softplusf(m2[c * 9 + j]);
        p.m3[j] = softplusf(m3[c * 9 + j]);
    }
    p.b4 = b4[c];

    float* g = lut + (size_t)c * LSTRIDE;
    for (int k = threadIdx.x; k < NK; k += 256) {
        float u  = fmaf((float)k, 1.0f / 64.0f, -8.0f);
        float lo = evalnet_acc(u - 0.5f, p);
        float hi = evalnet_acc(u + 0.5f, p);
        // |sigmoid(s*hi)-sigmoid(s*lo)| == |sigmoid(hi)-sigmoid(lo)| for s=+-1
        float l = fabsf(sigmoid_acc(hi) - sigmoid_acc(lo));
        g[k] = fmaxf(l, 1e-9f);
    }
}

// Main: u = x+noise; likelihood = lerp into per-channel LUT held in LDS.
__global__ __launch_bounds__(256) void eb_lut_main(const float4* __restrict__ x,
                                                   const float4* __restrict__ nz,
                                                   const float* __restrict__ lut,
                                                   float4* __restrict__ out,
                                                   float4* __restrict__ lik) {
    __shared__ float slut[NK];
    int slice = blockIdx.x;          // 0..3071, one (b,c) slice each
    int c = slice % NCH;
    const float* g = lut + (size_t)c * LSTRIDE;

    int t = threadIdx.x;
    ((float4*)slut)[t] = ((const float4*)g)[t];   // floats 0..1023
    if (t == 0) slut[1024] = g[1024];
    __syncthreads();

    int base = slice * (SLICE / 4);
#pragma unroll
    for (int j = 0; j < SLICE / 4 / 256; ++j) {
        int i = base + t + j * 256;
        float4 xv = x[i];
        float4 nv = nz[i];
        float u0 = xv.x + nv.x, u1 = xv.y + nv.y, u2 = xv.z + nv.z, u3 = xv.w + nv.w;
        out[i] = make_float4(u0, u1, u2, u3);

        float4 lv;
        float* lp = (float*)&lv;
        float us[4] = {u0, u1, u2, u3};
#pragma unroll
        for (int s = 0; s < 4; ++s) {
            float tt = fmaf(us[s], 64.0f, 512.0f);
            tt = fminf(fmaxf(tt, 0.0f), 1023.99f);
            int ii = (int)tt;
            float fr = tt - (float)ii;
            float a = slut[ii];
            float b = slut[ii + 1];
            lp[s] = fmaf(fr, b - a, a);
        }
        lik[i] = lv;
    }
}

// ---------------- fallback (direct compute, R0 kernel) ----------------
struct Params {
    float m0[3], b0[3], tf0[3];
    float m1[9], b1[3], tf1[3];
    float m2[9], b2[3], tf2[3];
    float m3[9], b3[3], tf3[3];
    float m4[3], b4;
    float pad[6];
};

__global__ void eb_precompute(const float* __restrict__ m0, const float* __restrict__ b0, const float* __restrict__ f0,
                              const float* __restrict__ m1, const float* __restrict__ b1, const float* __restrict__ f1,
                              const float* __restrict__ m2, const float* __restrict__ b2, const float* __restrict__ f2,
                              const float* __restrict__ m3, const float* __restrict__ b3, const float* __restrict__ f3,
                              const float* __restrict__ m4, const float* __restrict__ b4,
                              Params* __restrict__ P) {
    int c = blockIdx.x * blockDim.x + threadIdx.x;
    if (c >= NCH) return;
    Params p;
#pragma unroll
    for (int j = 0; j < 3; ++j) {
        p.m0[j]  = softplusf(m0[c * 3 + j]);
        p.b0[j]  = b0[c * 3 + j];
        p.tf0[j] = tanhf(f0[c * 3 + j]);
        p.b1[j]  = b1[c * 3 + j];
        p.tf1[j] = tanhf(f1[c * 3 + j]);
        p.b2[j]  = b2[c * 3 + j];
        p.tf2[j] = tanhf(f2[c * 3 + j]);
        p.b3[j]  = b3[c * 3 + j];
        p.tf3[j] = tanhf(f3[c * 3 + j]);
        p.m4[j]  = softplusf(m4[c * 3 + j]);
    }
#pragma unroll
    for (int j = 0; j < 9; ++j) {
        p.m1[j] = softplusf(m1[c * 9 + j]);
        p.m2[j] = softplusf(m2[c * 9 + j]);
        p.m3[j] = softplusf(m3[c * 9 + j]);
    }
    p.b4 = b4[c];
#pragma unroll
    for (int j = 0; j < 6; ++j) p.pad[j] = 0.f;
    P[c] = p;
}

__device__ __forceinline__ float fast_tanh(float x) {
    float e = __expf(2.0f * x);
    return 1.0f - 2.0f * __builtin_amdgcn_rcpf(e + 1.0f);
}
__device__ __forceinline__ float fast_sigmoid(float x) {
    return __builtin_amdgcn_rcpf(1.0f + __expf(-x));
}
__device__ __forceinline__ float evalnet(float u, const Params& p) {
    float v0 = fmaf(p.m0[0], u, p.b0[0]);
    float v1 = fmaf(p.m0[1], u, p.b0[1]);
    float v2 = fmaf(p.m0[2], u, p.b0[2]);
    v0 = fmaf(p.tf0[0], fast_tanh(v0), v0);
    v1 = fmaf(p.tf0[1], fast_tanh(v1), v1);
    v2 = fmaf(p.tf0[2], fast_tanh(v2), v2);
    float w0 = fmaf(p.m1[0], v0, fmaf(p.m1[1], v1, fmaf(p.m1[2], v2, p.b1[0])));
    float w1 = fmaf(p.m1[3], v0, fmaf(p.m1[4], v1, fmaf(p.m1[5], v2, p.b1[1])));
    float w2 = fmaf(p.m1[6], v0, fmaf(p.m1[7], v1, fmaf(p.m1[8], v2, p.b1[2])));
    w0 = fmaf(p.tf1[0], fast_tanh(w0), w0);
    w1 = fmaf(p.tf1[1], fast_tanh(w1), w1);
    w2 = fmaf(p.tf1[2], fast_tanh(w2), w2);
    float y0 = fmaf(p.m2[0], w0, fmaf(p.m2[1], w1, fmaf(p.m2[2], w2, p.b2[0])));
    float y1 = fmaf(p.m2[3], w0, fmaf(p.m2[4], w1, fmaf(p.m2[5], w2, p.b2[1])));
    float y2 = fmaf(p.m2[6], w0, fmaf(p.m2[7], w1, fmaf(p.m2[8], w2, p.b2[2])));
    y0 = fmaf(p.tf2[0], fast_tanh(y0), y0);
    y1 = fmaf(p.tf2[1], fast_tanh(y1), y1);
    y2 = fmaf(p.tf2[2], fast_tanh(y2), y2);
    float z0 = fmaf(p.m3[0], y0, fmaf(p.m3[1], y1, fmaf(p.m3[2], y2, p.b3[0])));
    float z1 = fmaf(p.m3[3], y0, fmaf(p.m3[4], y1, fmaf(p.m3[5], y2, p.b3[1])));
    float z2 = fmaf(p.m3[6], y0, fmaf(p.m3[7], y1, fmaf(p.m3[8], y2, p.b3[2])));
    z0 = fmaf(p.tf3[0], fast_tanh(z0), z0);
    z1 = fmaf(p.tf3[1], fast_tanh(z1), z1);
    z2 = fmaf(p.tf3[2], fast_tanh(z2), z2);
    return fmaf(p.m4[0], z0, fmaf(p.m4[1], z1, fmaf(p.m4[2], z2, p.b4)));
}
__device__ __forceinline__ float likelihood_of(float u, const Params& p) {
    float lo = evalnet(u - 0.5f, p);
    float hi = evalnet(u + 0.5f, p);
    float l = fabsf(fast_sigmoid(hi) - fast_sigmoid(lo));
    return fmaxf(l, 1e-9f);
}
__global__ __launch_bounds__(256) void eb_main(const float4* __restrict__ x,
                                               const float4* __restrict__ nz,
                                               const Params* __restrict__ P,
                                               float4* __restrict__ out,
                                               float4* __restrict__ lik) {
    int stride = gridDim.x * blockDim.x;
    for (int i = blockIdx.x * blockDim.x + threadIdx.x; i < NV4; i += stride) {
        int c = __builtin_amdgcn_readfirstlane((i >> 10) % NCH);
        const Params& p = P[c];
        float4 xv = x[i];
        float4 nv = nz[i];
        float u0 = xv.x + nv.x, u1 = xv.y + nv.y, u2 = xv.z + nv.z, u3 = xv.w + nv.w;
        out[i] = make_float4(u0, u1, u2, u3);
        lik[i] = make_float4(likelihood_of(u0, p), likelihood_of(u1, p),
                             likelihood_of(u2, p), likelihood_of(u3, p));
    }
}

extern "C" void kernel_launch(void* const* d_in, const int* in_sizes, int n_in,
                              void* d_out, int out_size, void* d_ws, size_t ws_size,
                              hipStream_t stream) {
    const float* x  = (const float*)d_in[0];
    const float* nz = (const float*)d_in[1];
    const float* m0 = (const float*)d_in[2];
    const float* b0 = (const float*)d_in[3];
    const float* f0 = (const float*)d_in[4];
    const float* m1 = (const float*)d_in[5];
    const float* b1 = (const float*)d_in[6];
    const float* f1 = (const float*)d_in[7];
    const float* m2 = (const float*)d_in[8];
    const float* b2 = (const float*)d_in[9];
    const float* f2 = (const float*)d_in[10];
    const float* m3 = (const float*)d_in[11];
    const float* b3 = (const float*)d_in[12];
    const float* f3 = (const float*)d_in[13];
    const float* m4 = (const float*)d_in[14];
    const float* b4 = (const float*)d_in[15];

    float* out = (float*)d_out;
    float* lik = out + TOTAL;

    if (ws_size >= LUT_BYTES) {
        float* lut = (float*)d_ws;
        eb_build_lut<<<NCH, 256, 0, stream>>>(m0, b0, f0, m1, b1, f1, m2, b2, f2,
                                              m3, b3, f3, m4, b4, lut);
        eb_lut_main<<<NSLICE, 256, 0, stream>>>((const float4*)x, (const float4*)nz,
                                                lut, (float4*)out, (float4*)lik);
    } else {
        Params* P = (Params*)d_ws;
        eb_precompute<<<1, 256, 0, stream>>>(m0, b0, f0, m1, b1, f1, m2, b2, f2,
                                             m3, b3, f3, m4, b4, P);
        eb_main<<<2048, 256, 0, stream>>>((const float4*)x, (const float4*)nz, P,
                                          (float4*)out, (float4*)lik);
    }
}